// Round 18
// baseline (133.534 us; speedup 1.0000x reference)
//
#include <hip/hip_runtime.h>

#define HW  (1024u*1024u)
#define CHW (2u*HW)
#define MAXP 65536u
#define LABEL_OFF 1048576u
#define SCORE_OFF 1572864u
#define NINF (-3.0e38f)
#define PAIRS_PER_CHUNK 512u

__device__ __forceinline__ float max3f(float a, float b, float c) {
    return fmaxf(fmaxf(a, b), c);
}

// ---- A: 7x7 NMS mask + in-order pair emission (R13 body), x3 internal repeat ----
// MEASUREMENT ROUND: body repeated 3x (idempotent) so the dispatch is long
// enough to appear in rocprof top-5 with its own counters. dur/3 ~= true mask.
__global__ __launch_bounds__(256, 4) void mask_kernel(const float* __restrict__ map,
                                                      uint2* __restrict__ pairs,
                                                      unsigned* __restrict__ chunkCount) {
    __shared__ float4 rowbuf[2][2][258];       // [parity][rowInPair][col4+pads]
    __shared__ unsigned swscan[4];
    int bid0 = blockIdx.x;
    int bid = (bid0 & 7) * 128 + (bid0 >> 3);  // XCD swizzle (bijective: 1024 % 8 == 0)
    int tid = threadIdx.x;
    int stripe = bid & 63;
    int img = bid >> 6;                        // b*2 + c
    int r0 = stripe << 4;
    int lane = tid & 63, wv = tid >> 6;
    const size_t pbase = (size_t)bid * PAIRS_PER_CHUNK;

    if (tid < 8) {                             // NINF pads at [*][*][0] and [*][*][257]
        float4 n4 = make_float4(NINF, NINF, NINF, NINF);
        rowbuf[(tid >> 2) & 1][(tid >> 1) & 1][(tid & 1) * 257] = n4;
    }

    // column-validity nibble (cols 6..1017 valid)
    int c0 = tid * 4;
    int cvm = 0;
    #pragma unroll
    for (int j = 0; j < 4; ++j) {
        int cc = c0 + j;
        if (cc >= 6 && cc <= 1017) cvm |= (1 << j);
    }

    unsigned chunkOff = 0;

    #pragma unroll 1
    for (int rep = 0; rep < 3; ++rep) {
        // launder base so the compiler cannot CSE loads across reps
        unsigned zoff = 0;
        asm volatile("" : "+v"(zoff));
        const float4* __restrict__ base =
            (const float4*)(map + ((size_t)img << 20)) + zoff;

        chunkOff = 0;

        // rolling 12-slot window: input row q -> slot (q - r0 + 3) mod 12
        float4 w[12];
        #pragma unroll
        for (int k = 0; k < 10; ++k) {         // rows r0-3 .. r0+6
            int rr = r0 - 3 + k;
            w[k] = ((unsigned)rr < 1024u) ? base[rr * 256 + tid]
                                          : make_float4(NINF, NINF, NINF, NINF);
        }

        #pragma unroll
        for (int p = 0; p < 8; ++p) {          // pair rows rA = r0+2p, rB = rA+1
            int rA = r0 + 2 * p;
            if (p < 6) {                       // prefetch rows rA+7, rA+8 (for iter p+2)
                int q1 = rA + 7, q2 = rA + 8;
                w[(2 * p + 10) % 12] = ((unsigned)q1 < 1024u) ? base[q1 * 256 + tid]
                                                              : make_float4(NINF, NINF, NINF, NINF);
                w[(2 * p + 11) % 12] = ((unsigned)q2 < 1024u) ? base[q2 * 256 + tid]
                                                              : make_float4(NINF, NINF, NINF, NINF);
            }
            float4 s0 = w[(2 * p + 0) % 12], s1 = w[(2 * p + 1) % 12];
            float4 s2 = w[(2 * p + 2) % 12], s3 = w[(2 * p + 3) % 12];
            float4 s4 = w[(2 * p + 4) % 12], s5 = w[(2 * p + 5) % 12];
            float4 s6 = w[(2 * p + 6) % 12], s7 = w[(2 * p + 7) % 12];

            float4 c6, vmA, vmB;
            c6.x = fmaxf(max3f(s1.x, s2.x, s3.x), max3f(s4.x, s5.x, s6.x));
            c6.y = fmaxf(max3f(s1.y, s2.y, s3.y), max3f(s4.y, s5.y, s6.y));
            c6.z = fmaxf(max3f(s1.z, s2.z, s3.z), max3f(s4.z, s5.z, s6.z));
            c6.w = fmaxf(max3f(s1.w, s2.w, s3.w), max3f(s4.w, s5.w, s6.w));
            vmA.x = fmaxf(c6.x, s0.x); vmB.x = fmaxf(c6.x, s7.x);
            vmA.y = fmaxf(c6.y, s0.y); vmB.y = fmaxf(c6.y, s7.y);
            vmA.z = fmaxf(c6.z, s0.z); vmB.z = fmaxf(c6.z, s7.z);
            vmA.w = fmaxf(c6.w, s0.w); vmB.w = fmaxf(c6.w, s7.w);

            rowbuf[p & 1][0][tid + 1] = vmA;
            rowbuf[p & 1][1][tid + 1] = vmB;
            __syncthreads();
            float4 LA = rowbuf[p & 1][0][tid], RA = rowbuf[p & 1][0][tid + 2];
            float4 LB = rowbuf[p & 1][1][tid], RB = rowbuf[p & 1][1][tid + 2];

            float mA0 = max3f(max3f(LA.y, LA.z, LA.w),  max3f(vmA.x, vmA.y, vmA.z), vmA.w);
            float mA1 = max3f(max3f(LA.z, LA.w, vmA.x), max3f(vmA.y, vmA.z, vmA.w), RA.x);
            float mA2 = max3f(max3f(LA.w, vmA.x, vmA.y), max3f(vmA.z, vmA.w, RA.x), RA.y);
            float mA3 = max3f(max3f(vmA.x, vmA.y, vmA.z), max3f(vmA.w, RA.x, RA.y), RA.z);
            float mB0 = max3f(max3f(LB.y, LB.z, LB.w),  max3f(vmB.x, vmB.y, vmB.z), vmB.w);
            float mB1 = max3f(max3f(LB.z, LB.w, vmB.x), max3f(vmB.y, vmB.z, vmB.w), RB.x);
            float mB2 = max3f(max3f(LB.w, vmB.x, vmB.y), max3f(vmB.z, vmB.w, RB.x), RB.y);
            float mB3 = max3f(max3f(vmB.x, vmB.y, vmB.z), max3f(vmB.w, RB.x, RB.y), RB.z);

            float4 ctrA = s3, ctrB = s4;        // original rows rA, rB
            int fA0 = (ctrA.x == mA0) & (ctrA.x > 0.5f);
            int fA1 = (ctrA.y == mA1) & (ctrA.y > 0.5f);
            int fA2 = (ctrA.z == mA2) & (ctrA.z > 0.5f);
            int fA3 = (ctrA.w == mA3) & (ctrA.w > 0.5f);
            int fB0 = (ctrB.x == mB0) & (ctrB.x > 0.5f);
            int fB1 = (ctrB.y == mB1) & (ctrB.y > 0.5f);
            int fB2 = (ctrB.z == mB2) & (ctrB.z > 0.5f);
            int fB3 = (ctrB.w == mB3) & (ctrB.w > 0.5f);
            int nibA = (fA0 | (fA1 << 1) | (fA2 << 2) | (fA3 << 3)) & cvm;
            int nibB = (fB0 | (fB1 << 1) | (fB2 << 2) | (fB3 << 3)) & cvm;
            int rowokA = (rA >= 6) & (rA <= 1017);
            int rowokB = ((rA + 1) >= 6) & ((rA + 1) <= 1017);
            nibA = rowokA ? nibA : 0;
            nibB = rowokB ? nibB : 0;

            unsigned packed = (unsigned)__popc((unsigned)nibA)
                            | ((unsigned)__popc((unsigned)nibB) << 16);
            unsigned incl = packed;
            #pragma unroll
            for (int off = 1; off < 64; off <<= 1) {
                unsigned nn = __shfl_up(incl, off, 64);
                if (lane >= off) incl += nn;
            }
            if (lane == 63) swscan[wv] = incl;
            __syncthreads();
            unsigned excl = incl - packed;
            unsigned preA = 0, preB = 0, sumA = 0, sumB = 0;
            #pragma unroll
            for (int k = 0; k < 4; ++k) {
                unsigned sv = swscan[k];
                if (k < wv) { preA += sv & 0xFFFFu; preB += sv >> 16; }
                sumA += sv & 0xFFFFu; sumB += sv >> 16;
            }
            unsigned posA = chunkOff + preA + (excl & 0xFFFFu);
            unsigned posB = chunkOff + sumA + preB + (excl >> 16);
            chunkOff += sumA + sumB;

            unsigned flatbase = ((unsigned)(img & 1) << 20) | ((unsigned)rA << 10)
                              | ((unsigned)tid * 4u);
            if (nibA & 1) pairs[pbase + posA++] = make_uint2(flatbase + 0u, __float_as_uint(ctrA.x));
            if (nibA & 2) pairs[pbase + posA++] = make_uint2(flatbase + 1u, __float_as_uint(ctrA.y));
            if (nibA & 4) pairs[pbase + posA++] = make_uint2(flatbase + 2u, __float_as_uint(ctrA.z));
            if (nibA & 8) pairs[pbase + posA++] = make_uint2(flatbase + 3u, __float_as_uint(ctrA.w));
            if (nibB & 1) pairs[pbase + posB++] = make_uint2(flatbase + 1024u, __float_as_uint(ctrB.x));
            if (nibB & 2) pairs[pbase + posB++] = make_uint2(flatbase + 1025u, __float_as_uint(ctrB.y));
            if (nibB & 4) pairs[pbase + posB++] = make_uint2(flatbase + 1026u, __float_as_uint(ctrB.z));
            if (nibB & 8) pairs[pbase + posB++] = make_uint2(flatbase + 1027u, __float_as_uint(ctrB.w));
        }
    }

    if (tid == 0) chunkCount[bid] = chunkOff;   // chunk linear id == bid (= b*128+cib)
}

// ---- B: scan + coalesced scatter + tail pad (R13 body, unchanged) ----
__global__ __launch_bounds__(512) void scan_scatter(const uint2* __restrict__ pairs,
                                                    const unsigned* __restrict__ chunkCount,
                                                    float* __restrict__ out) {
    int bid0 = blockIdx.x;
    int blk = (bid0 & 7) * 128 + (bid0 >> 3);   // match mask's chunk->XCD mapping
    int b = blk >> 7, cib = blk & 127;
    int tid = threadIdx.x;
    int lane = tid & 63, wv = tid >> 6;         // wv 0..7

    __shared__ unsigned long long sw[8];
    __shared__ unsigned sbase, stotal;

    unsigned cc = (tid < 128) ? chunkCount[b * 128 + tid] : 0u;
    unsigned long long v = ((tid < cib) ? (unsigned long long)cc : 0ull)
                         | ((unsigned long long)cc << 32);
    for (int off = 32; off; off >>= 1) v += __shfl_down(v, off, 64);
    if (lane == 0) sw[wv] = v;
    __syncthreads();
    if (tid == 0) {
        unsigned long long t = sw[0] + sw[1] + sw[2] + sw[3] + sw[4] + sw[5] + sw[6] + sw[7];
        sbase  = (unsigned)t;
        stotal = (unsigned)(t >> 32);
    }
    __syncthreads();

    unsigned n = chunkCount[blk];
    if (n > PAIRS_PER_CHUNK) n = PAIRS_PER_CHUNK;
    if ((unsigned)tid < n) {
        uint2 pr = pairs[(size_t)blk * PAIRS_PER_CHUNK + tid];
        unsigned slot = sbase + (unsigned)tid;
        if (slot < MAXP) {
            unsigned flat = pr.x;
            unsigned c = flat >> 20;
            unsigned h = (flat >> 10) & 1023u;
            unsigned wcol = flat & 1023u;
            unsigned o = b * MAXP + slot;
            out[2u * o]         = (float)wcol;           // x
            out[2u * o + 1]     = (float)h;              // y
            out[LABEL_OFF + o]  = (float)(c + 1u);       // label
            out[SCORE_OFF + o]  = __uint_as_float(pr.y); // score
        }
    }

    unsigned slot = ((unsigned)cib) * 512u + (unsigned)tid;
    if (slot >= stotal) {                        // slot < 65536 by construction
        unsigned o = b * MAXP + slot;
        float2 neg1; neg1.x = -1.0f; neg1.y = -1.0f;
        ((float2*)out)[o]   = neg1;              // coords (x,y) = -1
        out[LABEL_OFF + o]  = 0.0f;
        out[SCORE_OFF + o]  = 0.0f;
    }
}

extern "C" void kernel_launch(void* const* d_in, const int* in_sizes, int n_in,
                              void* d_out, int out_size, void* d_ws, size_t ws_size,
                              hipStream_t stream) {
    const float* map = (const float*)d_in[0];
    float* out = (float*)d_out;
    uint2* pairs = (uint2*)d_ws;                                 // 4 MB
    unsigned* chunkCount = (unsigned*)((char*)d_ws + 4194304);   // 1024 u32

    mask_kernel<<<1024, 256, 0, stream>>>(map, pairs, chunkCount);
    scan_scatter<<<1024, 512, 0, stream>>>(pairs, chunkCount, out);
}

// Round 19
// 29.516 us; speedup vs baseline: 4.5241x; 4.5241x over previous
//
#include <hip/hip_runtime.h>

#define HW  (1024u*1024u)
#define CHW (2u*HW)
#define MAXP 65536u
#define LABEL_OFF 1048576u
#define SCORE_OFF 1572864u
#define NINF (-3.0e38f)
#define PAIRS_PER_CHUNK 512u

__device__ __forceinline__ float max3f(float a, float b, float c) {
    return fmaxf(fmaxf(a, b), c);
}

// popcount of mask bits strictly below this lane (64-wide)
__device__ __forceinline__ unsigned mbcnt_lt(unsigned long long m) {
    unsigned lo = __builtin_amdgcn_mbcnt_lo((unsigned)m, 0u);
    return __builtin_amdgcn_mbcnt_hi((unsigned)(m >> 32), lo);
}

// ---- A: 7x7 NMS mask + in-order pair emission (ballot/mbcnt positions) ----
// 1024 blocks, XCD-swizzled; block = one 16-row stripe of one image = one chunk.
__global__ __launch_bounds__(256, 4) void mask_kernel(const float* __restrict__ map,
                                                      uint2* __restrict__ pairs,
                                                      unsigned* __restrict__ chunkCount) {
    __shared__ float4 rowbuf[2][2][258];       // [parity][rowInPair][col4+pads]
    __shared__ unsigned swscan[4];
    int bid0 = blockIdx.x;
    int bid = (bid0 & 7) * 128 + (bid0 >> 3);  // XCD swizzle (bijective: 1024 % 8 == 0)
    int tid = threadIdx.x;
    int stripe = bid & 63;
    int img = bid >> 6;                        // b*2 + c
    int r0 = stripe << 4;
    int lane = tid & 63, wv = tid >> 6;
    const float4* __restrict__ base = (const float4*)(map + ((size_t)img << 20));
    const size_t pbase = (size_t)bid * PAIRS_PER_CHUNK;

    if (tid < 8) {                             // NINF pads at [*][*][0] and [*][*][257]
        float4 n4 = make_float4(NINF, NINF, NINF, NINF);
        rowbuf[(tid >> 2) & 1][(tid >> 1) & 1][(tid & 1) * 257] = n4;
    }

    // column-validity nibble (cols 6..1017 valid)
    int c0 = tid * 4;
    int cvm = 0;
    #pragma unroll
    for (int j = 0; j < 4; ++j) {
        int cc = c0 + j;
        if (cc >= 6 && cc <= 1017) cvm |= (1 << j);
    }

    // rolling 12-slot window: input row q -> slot (q - r0 + 3) mod 12
    float4 w[12];
    #pragma unroll
    for (int k = 0; k < 10; ++k) {             // rows r0-3 .. r0+6
        int rr = r0 - 3 + k;
        w[k] = ((unsigned)rr < 1024u) ? base[rr * 256 + tid]
                                      : make_float4(NINF, NINF, NINF, NINF);
    }

    unsigned chunkOff = 0;                     // peaks emitted so far (block-uniform)

    #pragma unroll
    for (int p = 0; p < 8; ++p) {              // pair rows rA = r0+2p, rB = rA+1
        int rA = r0 + 2 * p;
        if (p < 6) {                           // prefetch rows rA+7, rA+8 (for iter p+2)
            int q1 = rA + 7, q2 = rA + 8;
            w[(2 * p + 10) % 12] = ((unsigned)q1 < 1024u) ? base[q1 * 256 + tid]
                                                          : make_float4(NINF, NINF, NINF, NINF);
            w[(2 * p + 11) % 12] = ((unsigned)q2 < 1024u) ? base[q2 * 256 + tid]
                                                          : make_float4(NINF, NINF, NINF, NINF);
        }
        float4 s0 = w[(2 * p + 0) % 12], s1 = w[(2 * p + 1) % 12];
        float4 s2 = w[(2 * p + 2) % 12], s3 = w[(2 * p + 3) % 12];
        float4 s4 = w[(2 * p + 4) % 12], s5 = w[(2 * p + 5) % 12];
        float4 s6 = w[(2 * p + 6) % 12], s7 = w[(2 * p + 7) % 12];

        // vertical: common6 = max(rows rA-2..rA+3); vmA = max(c6, rA-3); vmB = max(c6, rA+4)
        float4 c6, vmA, vmB;
        c6.x = fmaxf(max3f(s1.x, s2.x, s3.x), max3f(s4.x, s5.x, s6.x));
        c6.y = fmaxf(max3f(s1.y, s2.y, s3.y), max3f(s4.y, s5.y, s6.y));
        c6.z = fmaxf(max3f(s1.z, s2.z, s3.z), max3f(s4.z, s5.z, s6.z));
        c6.w = fmaxf(max3f(s1.w, s2.w, s3.w), max3f(s4.w, s5.w, s6.w));
        vmA.x = fmaxf(c6.x, s0.x); vmB.x = fmaxf(c6.x, s7.x);
        vmA.y = fmaxf(c6.y, s0.y); vmB.y = fmaxf(c6.y, s7.y);
        vmA.z = fmaxf(c6.z, s0.z); vmB.z = fmaxf(c6.z, s7.z);
        vmA.w = fmaxf(c6.w, s0.w); vmB.w = fmaxf(c6.w, s7.w);

        rowbuf[p & 1][0][tid + 1] = vmA;
        rowbuf[p & 1][1][tid + 1] = vmB;
        __syncthreads();
        float4 LA = rowbuf[p & 1][0][tid], RA = rowbuf[p & 1][0][tid + 2];
        float4 LB = rowbuf[p & 1][1][tid], RB = rowbuf[p & 1][1][tid + 2];

        // horizontal 7-max
        float mA0 = max3f(max3f(LA.y, LA.z, LA.w),  max3f(vmA.x, vmA.y, vmA.z), vmA.w);
        float mA1 = max3f(max3f(LA.z, LA.w, vmA.x), max3f(vmA.y, vmA.z, vmA.w), RA.x);
        float mA2 = max3f(max3f(LA.w, vmA.x, vmA.y), max3f(vmA.z, vmA.w, RA.x), RA.y);
        float mA3 = max3f(max3f(vmA.x, vmA.y, vmA.z), max3f(vmA.w, RA.x, RA.y), RA.z);
        float mB0 = max3f(max3f(LB.y, LB.z, LB.w),  max3f(vmB.x, vmB.y, vmB.z), vmB.w);
        float mB1 = max3f(max3f(LB.z, LB.w, vmB.x), max3f(vmB.y, vmB.z, vmB.w), RB.x);
        float mB2 = max3f(max3f(LB.w, vmB.x, vmB.y), max3f(vmB.z, vmB.w, RB.x), RB.y);
        float mB3 = max3f(max3f(vmB.x, vmB.y, vmB.z), max3f(vmB.w, RB.x, RB.y), RB.z);

        float4 ctrA = s3, ctrB = s4;            // original rows rA, rB
        int fA0 = (ctrA.x == mA0) & (ctrA.x > 0.5f);
        int fA1 = (ctrA.y == mA1) & (ctrA.y > 0.5f);
        int fA2 = (ctrA.z == mA2) & (ctrA.z > 0.5f);
        int fA3 = (ctrA.w == mA3) & (ctrA.w > 0.5f);
        int fB0 = (ctrB.x == mB0) & (ctrB.x > 0.5f);
        int fB1 = (ctrB.y == mB1) & (ctrB.y > 0.5f);
        int fB2 = (ctrB.z == mB2) & (ctrB.z > 0.5f);
        int fB3 = (ctrB.w == mB3) & (ctrB.w > 0.5f);
        int nibA = (fA0 | (fA1 << 1) | (fA2 << 2) | (fA3 << 3)) & cvm;
        int nibB = (fB0 | (fB1 << 1) | (fB2 << 2) | (fB3 << 3)) & cvm;
        int rowokA = (rA >= 6) & (rA <= 1017);
        int rowokB = ((rA + 1) >= 6) & ((rA + 1) <= 1017);
        nibA = rowokA ? nibA : 0;
        nibB = rowokB ? nibB : 0;

        // ---- positions via ballot + mbcnt (no shfl scan, no bpermute) ----
        unsigned long long bA0 = __ballot(nibA & 1), bA1 = __ballot(nibA & 2);
        unsigned long long bA2 = __ballot(nibA & 4), bA3 = __ballot(nibA & 8);
        unsigned long long bB0 = __ballot(nibB & 1), bB1 = __ballot(nibB & 2);
        unsigned long long bB2 = __ballot(nibB & 4), bB3 = __ballot(nibB & 8);
        unsigned preT_A = mbcnt_lt(bA0) + mbcnt_lt(bA1) + mbcnt_lt(bA2) + mbcnt_lt(bA3);
        unsigned preT_B = mbcnt_lt(bB0) + mbcnt_lt(bB1) + mbcnt_lt(bB2) + mbcnt_lt(bB3);
        unsigned sumA = (unsigned)(__popcll(bA0) + __popcll(bA1) + __popcll(bA2) + __popcll(bA3));
        unsigned sumB = (unsigned)(__popcll(bB0) + __popcll(bB1) + __popcll(bB2) + __popcll(bB3));

        if (lane == 0) swscan[wv] = sumA | (sumB << 16);
        __syncthreads();
        unsigned preA = 0, preB = 0, sumAall = 0, sumBall = 0;
        #pragma unroll
        for (int k = 0; k < 4; ++k) {
            unsigned sv = swscan[k];
            if (k < wv) { preA += sv & 0xFFFFu; preB += sv >> 16; }
            sumAall += sv & 0xFFFFu; sumBall += sv >> 16;
        }
        unsigned posA = chunkOff + preA + preT_A;
        unsigned posB = chunkOff + sumAall + preB + preT_B;
        chunkOff += sumAall + sumBall;

        unsigned flatbase = ((unsigned)(img & 1) << 20) | ((unsigned)rA << 10)
                          | ((unsigned)tid * 4u);
        if (nibA & 1) pairs[pbase + posA++] = make_uint2(flatbase + 0u, __float_as_uint(ctrA.x));
        if (nibA & 2) pairs[pbase + posA++] = make_uint2(flatbase + 1u, __float_as_uint(ctrA.y));
        if (nibA & 4) pairs[pbase + posA++] = make_uint2(flatbase + 2u, __float_as_uint(ctrA.z));
        if (nibA & 8) pairs[pbase + posA++] = make_uint2(flatbase + 3u, __float_as_uint(ctrA.w));
        if (nibB & 1) pairs[pbase + posB++] = make_uint2(flatbase + 1024u, __float_as_uint(ctrB.x));
        if (nibB & 2) pairs[pbase + posB++] = make_uint2(flatbase + 1025u, __float_as_uint(ctrB.y));
        if (nibB & 4) pairs[pbase + posB++] = make_uint2(flatbase + 1026u, __float_as_uint(ctrB.z));
        if (nibB & 8) pairs[pbase + posB++] = make_uint2(flatbase + 1027u, __float_as_uint(ctrB.w));
    }

    if (tid == 0) chunkCount[bid] = chunkOff;   // chunk linear id == bid (= b*128+cib)
}

// ---- B: fat scatter. 256 blocks x 1024 threads; block handles 4 chunks ----
__global__ __launch_bounds__(1024) void scan_scatter(const uint2* __restrict__ pairs,
                                                     const unsigned* __restrict__ chunkCount,
                                                     float* __restrict__ out) {
    int g = blockIdx.x;
    int b = g >> 5;                             // batch
    int cbase0 = (g & 31) * 4;                  // first chunk-in-batch of this block
    int tid = threadIdx.x;
    int lane = tid & 63, wv = tid >> 6;         // wv 0..15

    __shared__ unsigned sBase[128];
    __shared__ unsigned sCnt[128];
    __shared__ unsigned sTot[2];

    // full 128-chunk scan for this batch, once per block (2 waves)
    if (tid < 128) {
        unsigned c = chunkCount[b * 128 + tid];
        sCnt[tid] = c;
        unsigned incl = c;
        #pragma unroll
        for (int off = 1; off < 64; off <<= 1) {
            unsigned nn = __shfl_up(incl, off, 64);
            if (lane >= off) incl += nn;
        }
        if (lane == 63) sTot[wv] = incl;
        sBase[tid] = incl - c;
    }
    __syncthreads();
    if (tid >= 64 && tid < 128) sBase[tid] += sTot[0];
    __syncthreads();
    unsigned total = sTot[0] + sTot[1];

    int half = tid >> 9;                        // 0 or 1
    int idx  = tid & 511;
    #pragma unroll
    for (int k = 0; k < 2; ++k) {
        int cib = cbase0 + k * 2 + half;        // chunk in batch
        int blkC = b * 128 + cib;
        unsigned n = sCnt[cib];
        if (n > PAIRS_PER_CHUNK) n = PAIRS_PER_CHUNK;
        unsigned cb = sBase[cib];

        if ((unsigned)idx < n) {
            uint2 pr = pairs[(size_t)blkC * PAIRS_PER_CHUNK + idx];
            unsigned slot = cb + (unsigned)idx;
            if (slot < MAXP) {
                unsigned flat = pr.x;
                unsigned c = flat >> 20;
                unsigned h = (flat >> 10) & 1023u;
                unsigned wcol = flat & 1023u;
                unsigned o = b * MAXP + slot;
                float2 xy; xy.x = (float)wcol; xy.y = (float)h;
                ((float2*)out)[o]   = xy;                    // coords
                out[LABEL_OFF + o]  = (float)(c + 1u);       // label
                out[SCORE_OFF + o]  = __uint_as_float(pr.y); // score
            }
        }

        // tail padding for this chunk's 512-slot slice
        unsigned slot = ((unsigned)cib) * 512u + (unsigned)idx;
        if (slot >= total) {                     // slot < 65536 by construction
            unsigned o = b * MAXP + slot;
            float2 neg1; neg1.x = -1.0f; neg1.y = -1.0f;
            ((float2*)out)[o]   = neg1;
            out[LABEL_OFF + o]  = 0.0f;
            out[SCORE_OFF + o]  = 0.0f;
        }
    }
}

extern "C" void kernel_launch(void* const* d_in, const int* in_sizes, int n_in,
                              void* d_out, int out_size, void* d_ws, size_t ws_size,
                              hipStream_t stream) {
    const float* map = (const float*)d_in[0];
    float* out = (float*)d_out;
    uint2* pairs = (uint2*)d_ws;                                 // 4 MB
    unsigned* chunkCount = (unsigned*)((char*)d_ws + 4194304);   // 1024 u32

    mask_kernel<<<1024, 256, 0, stream>>>(map, pairs, chunkCount);
    scan_scatter<<<256, 1024, 0, stream>>>(pairs, chunkCount, out);
}

// Round 20
// 28.244 us; speedup vs baseline: 4.7278x; 1.0450x over previous
//
#include <hip/hip_runtime.h>

#define HW  (1024u*1024u)
#define CHW (2u*HW)
#define MAXP 65536u
#define LABEL_OFF 1048576u
#define SCORE_OFF 1572864u
#define NINF (-3.0e38f)
#define PAIRS_PER_CHUNK 512u

__device__ __forceinline__ float max3f(float a, float b, float c) {
    return fmaxf(fmaxf(a, b), c);
}

// popcount of mask bits strictly below this lane (64-wide)
__device__ __forceinline__ unsigned mbcnt_lt(unsigned long long m) {
    unsigned lo = __builtin_amdgcn_mbcnt_lo((unsigned)m, 0u);
    return __builtin_amdgcn_mbcnt_hi((unsigned)(m >> 32), lo);
}

// ---- A: 7x7 NMS mask + in-order pair emission (ballot/mbcnt positions) ----
// 1024 blocks, XCD-swizzled; block = one 16-row stripe of one image = one chunk.
// KEY CHANGE vs R19: prefetch for iter p+2 is issued AFTER iter p's barrier, so
// the barrier's vmcnt(0) drain never waits on a just-issued prefetch (the load
// crosses only iter p+1's barrier, a full iteration after issue).
__global__ __launch_bounds__(256, 4) void mask_kernel(const float* __restrict__ map,
                                                      uint2* __restrict__ pairs,
                                                      unsigned* __restrict__ chunkCount) {
    __shared__ float4 rowbuf[2][2][258];       // [parity][rowInPair][col4+pads]
    __shared__ unsigned swscan[4];
    int bid0 = blockIdx.x;
    int bid = (bid0 & 7) * 128 + (bid0 >> 3);  // XCD swizzle (bijective: 1024 % 8 == 0)
    int tid = threadIdx.x;
    int stripe = bid & 63;
    int img = bid >> 6;                        // b*2 + c
    int r0 = stripe << 4;
    int lane = tid & 63, wv = tid >> 6;
    const float4* __restrict__ base = (const float4*)(map + ((size_t)img << 20));
    const size_t pbase = (size_t)bid * PAIRS_PER_CHUNK;

    if (tid < 8) {                             // NINF pads at [*][*][0] and [*][*][257]
        float4 n4 = make_float4(NINF, NINF, NINF, NINF);
        rowbuf[(tid >> 2) & 1][(tid >> 1) & 1][(tid & 1) * 257] = n4;
    }

    // column-validity nibble (cols 6..1017 valid)
    int c0 = tid * 4;
    int cvm = 0;
    #pragma unroll
    for (int j = 0; j < 4; ++j) {
        int cc = c0 + j;
        if (cc >= 6 && cc <= 1017) cvm |= (1 << j);
    }

    // rolling 12-slot window: input row q -> slot (q - r0 + 3) mod 12
    float4 w[12];
    #pragma unroll
    for (int k = 0; k < 10; ++k) {             // rows r0-3 .. r0+6
        int rr = r0 - 3 + k;
        w[k] = ((unsigned)rr < 1024u) ? base[rr * 256 + tid]
                                      : make_float4(NINF, NINF, NINF, NINF);
    }

    unsigned chunkOff = 0;                     // peaks emitted so far (block-uniform)

    #pragma unroll
    for (int p = 0; p < 8; ++p) {              // pair rows rA = r0+2p, rB = rA+1
        int rA = r0 + 2 * p;

        float4 s0 = w[(2 * p + 0) % 12], s1 = w[(2 * p + 1) % 12];
        float4 s2 = w[(2 * p + 2) % 12], s3 = w[(2 * p + 3) % 12];
        float4 s4 = w[(2 * p + 4) % 12], s5 = w[(2 * p + 5) % 12];
        float4 s6 = w[(2 * p + 6) % 12], s7 = w[(2 * p + 7) % 12];

        // vertical: common6 = max(rows rA-2..rA+3); vmA = max(c6, rA-3); vmB = max(c6, rA+4)
        float4 c6, vmA, vmB;
        c6.x = fmaxf(max3f(s1.x, s2.x, s3.x), max3f(s4.x, s5.x, s6.x));
        c6.y = fmaxf(max3f(s1.y, s2.y, s3.y), max3f(s4.y, s5.y, s6.y));
        c6.z = fmaxf(max3f(s1.z, s2.z, s3.z), max3f(s4.z, s5.z, s6.z));
        c6.w = fmaxf(max3f(s1.w, s2.w, s3.w), max3f(s4.w, s5.w, s6.w));
        vmA.x = fmaxf(c6.x, s0.x); vmB.x = fmaxf(c6.x, s7.x);
        vmA.y = fmaxf(c6.y, s0.y); vmB.y = fmaxf(c6.y, s7.y);
        vmA.z = fmaxf(c6.z, s0.z); vmB.z = fmaxf(c6.z, s7.z);
        vmA.w = fmaxf(c6.w, s0.w); vmB.w = fmaxf(c6.w, s7.w);

        rowbuf[p & 1][0][tid + 1] = vmA;
        rowbuf[p & 1][1][tid + 1] = vmB;
        __syncthreads();

        // ---- post-barrier prefetch (rows rA+7, rA+8; consumed at iter p+2) ----
        if (p < 6) {
            int q1 = rA + 7, q2 = rA + 8;
            w[(2 * p + 10) % 12] = ((unsigned)q1 < 1024u) ? base[q1 * 256 + tid]
                                                          : make_float4(NINF, NINF, NINF, NINF);
            w[(2 * p + 11) % 12] = ((unsigned)q2 < 1024u) ? base[q2 * 256 + tid]
                                                          : make_float4(NINF, NINF, NINF, NINF);
        }

        float4 LA = rowbuf[p & 1][0][tid], RA = rowbuf[p & 1][0][tid + 2];
        float4 LB = rowbuf[p & 1][1][tid], RB = rowbuf[p & 1][1][tid + 2];

        // horizontal 7-max
        float mA0 = max3f(max3f(LA.y, LA.z, LA.w),  max3f(vmA.x, vmA.y, vmA.z), vmA.w);
        float mA1 = max3f(max3f(LA.z, LA.w, vmA.x), max3f(vmA.y, vmA.z, vmA.w), RA.x);
        float mA2 = max3f(max3f(LA.w, vmA.x, vmA.y), max3f(vmA.z, vmA.w, RA.x), RA.y);
        float mA3 = max3f(max3f(vmA.x, vmA.y, vmA.z), max3f(vmA.w, RA.x, RA.y), RA.z);
        float mB0 = max3f(max3f(LB.y, LB.z, LB.w),  max3f(vmB.x, vmB.y, vmB.z), vmB.w);
        float mB1 = max3f(max3f(LB.z, LB.w, vmB.x), max3f(vmB.y, vmB.z, vmB.w), RB.x);
        float mB2 = max3f(max3f(LB.w, vmB.x, vmB.y), max3f(vmB.z, vmB.w, RB.x), RB.y);
        float mB3 = max3f(max3f(vmB.x, vmB.y, vmB.z), max3f(vmB.w, RB.x, RB.y), RB.z);

        float4 ctrA = s3, ctrB = s4;            // original rows rA, rB
        int fA0 = (ctrA.x == mA0) & (ctrA.x > 0.5f);
        int fA1 = (ctrA.y == mA1) & (ctrA.y > 0.5f);
        int fA2 = (ctrA.z == mA2) & (ctrA.z > 0.5f);
        int fA3 = (ctrA.w == mA3) & (ctrA.w > 0.5f);
        int fB0 = (ctrB.x == mB0) & (ctrB.x > 0.5f);
        int fB1 = (ctrB.y == mB1) & (ctrB.y > 0.5f);
        int fB2 = (ctrB.z == mB2) & (ctrB.z > 0.5f);
        int fB3 = (ctrB.w == mB3) & (ctrB.w > 0.5f);
        int nibA = (fA0 | (fA1 << 1) | (fA2 << 2) | (fA3 << 3)) & cvm;
        int nibB = (fB0 | (fB1 << 1) | (fB2 << 2) | (fB3 << 3)) & cvm;
        int rowokA = (rA >= 6) & (rA <= 1017);
        int rowokB = ((rA + 1) >= 6) & ((rA + 1) <= 1017);
        nibA = rowokA ? nibA : 0;
        nibB = rowokB ? nibB : 0;

        // ---- positions via ballot + mbcnt (no shfl scan, no bpermute) ----
        unsigned long long bA0 = __ballot(nibA & 1), bA1 = __ballot(nibA & 2);
        unsigned long long bA2 = __ballot(nibA & 4), bA3 = __ballot(nibA & 8);
        unsigned long long bB0 = __ballot(nibB & 1), bB1 = __ballot(nibB & 2);
        unsigned long long bB2 = __ballot(nibB & 4), bB3 = __ballot(nibB & 8);
        unsigned preT_A = mbcnt_lt(bA0) + mbcnt_lt(bA1) + mbcnt_lt(bA2) + mbcnt_lt(bA3);
        unsigned preT_B = mbcnt_lt(bB0) + mbcnt_lt(bB1) + mbcnt_lt(bB2) + mbcnt_lt(bB3);
        unsigned sumA = (unsigned)(__popcll(bA0) + __popcll(bA1) + __popcll(bA2) + __popcll(bA3));
        unsigned sumB = (unsigned)(__popcll(bB0) + __popcll(bB1) + __popcll(bB2) + __popcll(bB3));

        if (lane == 0) swscan[wv] = sumA | (sumB << 16);
        __syncthreads();
        unsigned preA = 0, preB = 0, sumAall = 0, sumBall = 0;
        #pragma unroll
        for (int k = 0; k < 4; ++k) {
            unsigned sv = swscan[k];
            if (k < wv) { preA += sv & 0xFFFFu; preB += sv >> 16; }
            sumAall += sv & 0xFFFFu; sumBall += sv >> 16;
        }
        unsigned posA = chunkOff + preA + preT_A;
        unsigned posB = chunkOff + sumAall + preB + preT_B;
        chunkOff += sumAall + sumBall;

        unsigned flatbase = ((unsigned)(img & 1) << 20) | ((unsigned)rA << 10)
                          | ((unsigned)tid * 4u);
        if (nibA & 1) pairs[pbase + posA++] = make_uint2(flatbase + 0u, __float_as_uint(ctrA.x));
        if (nibA & 2) pairs[pbase + posA++] = make_uint2(flatbase + 1u, __float_as_uint(ctrA.y));
        if (nibA & 4) pairs[pbase + posA++] = make_uint2(flatbase + 2u, __float_as_uint(ctrA.z));
        if (nibA & 8) pairs[pbase + posA++] = make_uint2(flatbase + 3u, __float_as_uint(ctrA.w));
        if (nibB & 1) pairs[pbase + posB++] = make_uint2(flatbase + 1024u, __float_as_uint(ctrB.x));
        if (nibB & 2) pairs[pbase + posB++] = make_uint2(flatbase + 1025u, __float_as_uint(ctrB.y));
        if (nibB & 4) pairs[pbase + posB++] = make_uint2(flatbase + 1026u, __float_as_uint(ctrB.z));
        if (nibB & 8) pairs[pbase + posB++] = make_uint2(flatbase + 1027u, __float_as_uint(ctrB.w));
    }

    if (tid == 0) chunkCount[bid] = chunkOff;   // chunk linear id == bid (= b*128+cib)
}

// ---- B: fat scatter. 256 blocks x 1024 threads; block handles 4 chunks ----
__global__ __launch_bounds__(1024) void scan_scatter(const uint2* __restrict__ pairs,
                                                     const unsigned* __restrict__ chunkCount,
                                                     float* __restrict__ out) {
    int g = blockIdx.x;
    int b = g >> 5;                             // batch
    int cbase0 = (g & 31) * 4;                  // first chunk-in-batch of this block
    int tid = threadIdx.x;
    int lane = tid & 63, wv = tid >> 6;         // wv 0..15

    __shared__ unsigned sBase[128];
    __shared__ unsigned sCnt[128];
    __shared__ unsigned sTot[2];

    // full 128-chunk scan for this batch, once per block (2 waves)
    if (tid < 128) {
        unsigned c = chunkCount[b * 128 + tid];
        sCnt[tid] = c;
        unsigned incl = c;
        #pragma unroll
        for (int off = 1; off < 64; off <<= 1) {
            unsigned nn = __shfl_up(incl, off, 64);
            if (lane >= off) incl += nn;
        }
        if (lane == 63) sTot[wv] = incl;
        sBase[tid] = incl - c;
    }
    __syncthreads();
    if (tid >= 64 && tid < 128) sBase[tid] += sTot[0];
    __syncthreads();
    unsigned total = sTot[0] + sTot[1];

    int half = tid >> 9;                        // 0 or 1
    int idx  = tid & 511;
    #pragma unroll
    for (int k = 0; k < 2; ++k) {
        int cib = cbase0 + k * 2 + half;        // chunk in batch
        int blkC = b * 128 + cib;
        unsigned n = sCnt[cib];
        if (n > PAIRS_PER_CHUNK) n = PAIRS_PER_CHUNK;
        unsigned cb = sBase[cib];

        if ((unsigned)idx < n) {
            uint2 pr = pairs[(size_t)blkC * PAIRS_PER_CHUNK + idx];
            unsigned slot = cb + (unsigned)idx;
            if (slot < MAXP) {
                unsigned flat = pr.x;
                unsigned c = flat >> 20;
                unsigned h = (flat >> 10) & 1023u;
                unsigned wcol = flat & 1023u;
                unsigned o = b * MAXP + slot;
                float2 xy; xy.x = (float)wcol; xy.y = (float)h;
                ((float2*)out)[o]   = xy;                    // coords
                out[LABEL_OFF + o]  = (float)(c + 1u);       // label
                out[SCORE_OFF + o]  = __uint_as_float(pr.y); // score
            }
        }

        // tail padding for this chunk's 512-slot slice
        unsigned slot = ((unsigned)cib) * 512u + (unsigned)idx;
        if (slot >= total) {                     // slot < 65536 by construction
            unsigned o = b * MAXP + slot;
            float2 neg1; neg1.x = -1.0f; neg1.y = -1.0f;
            ((float2*)out)[o]   = neg1;
            out[LABEL_OFF + o]  = 0.0f;
            out[SCORE_OFF + o]  = 0.0f;
        }
    }
}

extern "C" void kernel_launch(void* const* d_in, const int* in_sizes, int n_in,
                              void* d_out, int out_size, void* d_ws, size_t ws_size,
                              hipStream_t stream) {
    const float* map = (const float*)d_in[0];
    float* out = (float*)d_out;
    uint2* pairs = (uint2*)d_ws;                                 // 4 MB
    unsigned* chunkCount = (unsigned*)((char*)d_ws + 4194304);   // 1024 u32

    mask_kernel<<<1024, 256, 0, stream>>>(map, pairs, chunkCount);
    scan_scatter<<<256, 1024, 0, stream>>>(pairs, chunkCount, out);
}